// Round 5
// baseline (32.021 us; speedup 1.0000x reference)
//
#include <hip/hip_runtime.h>
#include <math.h>

// Problem constants (fixed by reference setup)
#define B_TOTAL 32768
#define C_NUM   64
#define K_NUM   64
#define D_NUM   16

typedef float f32x4 __attribute__((ext_vector_type(4)));
typedef short s16x4 __attribute__((ext_vector_type(4)));

union Pack2 { unsigned int u[2]; s16x4 s; };

__device__ inline unsigned int cvt_pk_bf16(float a, float b) {
    unsigned int d;
    asm("v_cvt_pk_bf16_f32 %0, %1, %2" : "=v"(d) : "v"(a), "v"(b));
    return d;
}

__device__ inline unsigned int umax2(unsigned int a, unsigned int b) {
    return a > b ? a : b;   // nested pairs -> v_max3_u32 on gfx9+
}

// Full split for centroids (precomputed once per wave, outside hot loop).
__device__ inline void split_bf16(const float4 x, s16x4& hi, s16x4& lo) {
    Pack2 h, l;
    h.u[0] = cvt_pk_bf16(x.x, x.y);
    h.u[1] = cvt_pk_bf16(x.z, x.w);
    const float hx = __uint_as_float(h.u[0] << 16);
    const float hy = __uint_as_float(h.u[0] & 0xFFFF0000u);
    const float hz = __uint_as_float(h.u[1] << 16);
    const float hw = __uint_as_float(h.u[1] & 0xFFFF0000u);
    l.u[0] = cvt_pk_bf16(x.x - hx, x.y - hy);
    l.u[1] = cvt_pk_bf16(x.z - hz, x.w - hw);
    hi = h.s;
    lo = l.s;
}

#if __has_builtin(__builtin_amdgcn_mfma_f32_16x16x16bf16_1k)
__device__ inline f32x4 mfma16(s16x4 a, s16x4 b, f32x4 c) {
    return __builtin_amdgcn_mfma_f32_16x16x16bf16_1k(a, b, c, 0, 0, 0);
}
#define NEED_MFMA_FENCE 0
#else
__device__ inline f32x4 mfma16(s16x4 a, s16x4 b, f32x4 c) {
    asm("v_mfma_f32_16x16x16_bf16 %0, %1, %2, %0" : "+v"(c) : "v"(a), "v"(b));
    return c;
}
#define NEED_MFMA_FENCE 1
#endif

// Block: 1024 threads = 16 waves. Wave w owns codebook c = blockIdx.y*16 + w.
// Swapped MFMA: D = G(16k x 16d) * X(16d x 16b); lane holds col=b (lane&15),
// rows = k-entries (t*16 + hi*4 + j). C-operand pre-biased +64.0 -> results
// positive -> raw uint compare monotone. Low 8 mantissa bits carry (255-k):
// max(key) picks max value (256-ulp truncation), ties -> smallest k globally.
// Precision: dot = (Gh+Gl)*Xh; error ~ |g||x-xh| ~ 2^-9 -- flips bounded.
// NOTE (empirical, round 1): partial-64B stores from different blocks do NOT
// merge in L2 (7x write amp) -> blocks must span all 16 c's of a 64B output
// segment and write via LDS-staged contiguous float4s. Do not shrink blocks.
__global__ __launch_bounds__(1024, 8) void dpq_kernel(
    const float* __restrict__ inputs,     // (B, C, 16)
    const float* __restrict__ centroids,  // (C, 64, 16)
    float* __restrict__ out)              // codes(B*C) | mse(B*C) | cent copy
{
    const int tid  = threadIdx.x;
    const int w    = tid >> 6;
    const int lane = tid & 63;
    const int col  = lane & 15;   // b within tile / centroid k-row for A-frag
    const int hi   = lane >> 4;   // d/k sub-block

    const int cbase   = blockIdx.y * 16;
    const int c       = cbase + w;
    const int b_block = blockIdx.x * 256;

    __shared__ unsigned int lds_best[16][16][17];  // [b-tile][b][c-in-block]

    // Fold output-2 (centroid passthrough) into the y==0 blocks.
    if (blockIdx.y == 0 && tid < 128) {
        const float4* src = reinterpret_cast<const float4*>(centroids);
        float4* dst = reinterpret_cast<float4*>(out + (size_t)2 * B_TOTAL * C_NUM);
        dst[blockIdx.x * 128 + tid] = src[blockIdx.x * 128 + tid];
    }

    // Centroid fragments for this wave's codebook (reused across all b-tiles).
    s16x4 Gh[4], Gl[4];
#pragma unroll
    for (int t = 0; t < 4; ++t) {
        const float4 g = *reinterpret_cast<const float4*>(
            centroids + (size_t)c * (K_NUM * D_NUM) + (t * 16 + col) * D_NUM + hi * 4);
        split_bf16(g, Gh[t], Gl[t]);
    }

    const f32x4 bias4 = {64.0f, 64.0f, 64.0f, 64.0f};   // persistent C-operand
    const unsigned int kb8 = 255u - (unsigned)(hi * 4); // key index base

    // Per-lane input stream; step 16 rows (64 KB) per b-tile. Depth-3 prefetch.
    const float* xbase =
        inputs + (size_t)(b_block + col) * (C_NUM * D_NUM) + c * D_NUM + hi * 4;
#define XLD(i) (*reinterpret_cast<const float4*>(xbase + (size_t)(i) * 16 * (C_NUM * D_NUM)))
    float4 x0 = XLD(0);
    float4 x1 = XLD(1);
    float4 x2 = XLD(2);

#pragma unroll 4
    for (int bt = 0; bt < 16; ++bt) {
        const int pf = (bt + 3 < 16) ? bt + 3 : 15;
        const float4 xn = XLD(pf);

        // X high-part only (2 ops).
        Pack2 h;
        h.u[0] = cvt_pk_bf16(x0.x, x0.y);
        h.u[1] = cvt_pk_bf16(x0.z, x0.w);
        const s16x4 Xh = h.s;

        unsigned int part[4];
#pragma unroll
        for (int t = 0; t < 4; ++t) {
            f32x4 a = mfma16(Gh[t], Xh, bias4);
            a = mfma16(Gl[t], Xh, a);
#if NEED_MFMA_FENCE
            asm volatile("s_nop 7\n\ts_nop 7" :::);
#endif
            const unsigned int k0 =
                (__float_as_uint(a[0]) & 0xFFFFFF00u) | (kb8 - (unsigned)(t * 16 + 0));
            const unsigned int k1 =
                (__float_as_uint(a[1]) & 0xFFFFFF00u) | (kb8 - (unsigned)(t * 16 + 1));
            const unsigned int k2 =
                (__float_as_uint(a[2]) & 0xFFFFFF00u) | (kb8 - (unsigned)(t * 16 + 2));
            const unsigned int k3 =
                (__float_as_uint(a[3]) & 0xFFFFFF00u) | (kb8 - (unsigned)(t * 16 + 3));
            part[t] = umax2(umax2(umax2(k0, k1), k2), k3);   // max3 + max
        }
        unsigned int best =
            umax2(umax2(umax2(part[0], part[1]), part[2]), part[3]);

        // Combine the 4 hi-groups (other 48 candidates for this b).
        {
            const unsigned int o1 = __shfl_xor(best, 16);
            best = umax2(best, o1);
            const unsigned int o2 = __shfl_xor(best, 32);
            best = umax2(best, o2);
        }
        if (hi == 0) lds_best[bt][col][w] = best;
        x0 = x1;
        x1 = x2;
        x2 = xn;
    }
#undef XLD

    __syncthreads();

    // Coalesced bulk write: block region = 256 b x 16 c; decode here (once).
    {
        const int flat = tid * 4;              // 0..4092
        const int bl   = flat >> 4;            // local b row 0..255
        const int cc   = flat & 15;            // 0,4,8,12
        const int btb  = bl >> 4;
        const int bi   = bl & 15;
        float vc[4], vm[4];
#pragma unroll
        for (int r = 0; r < 4; ++r) {
            const unsigned int best = lds_best[btb][bi][cc + r];
            const int k = 255 - (int)(best & 255u);
            vc[r] = (float)((cbase + cc + r) * K_NUM + k);
            vm[r] = __uint_as_float(best & 0xFFFFFF00u) - 64.0f;
        }
        float* codes = out;
        float* mse   = out + (size_t)B_TOTAL * C_NUM;
        const size_t go = (size_t)(b_block + bl) * C_NUM + cbase + cc;
        *reinterpret_cast<float4*>(codes + go) = make_float4(vc[0], vc[1], vc[2], vc[3]);
        *reinterpret_cast<float4*>(mse   + go) = make_float4(vm[0], vm[1], vm[2], vm[3]);
    }
}

extern "C" void kernel_launch(void* const* d_in, const int* in_sizes, int n_in,
                              void* d_out, int out_size, void* d_ws, size_t ws_size,
                              hipStream_t stream) {
    const float* inputs    = (const float*)d_in[0];   // (32768, 64, 16) f32
    const float* centroids = (const float*)d_in[1];   // (64, 64, 16) f32
    float* out = (float*)d_out;

    dim3 grid(B_TOTAL / 256, C_NUM / 16);
    dim3 block(1024);
    dpq_kernel<<<grid, block, 0, stream>>>(inputs, centroids, out);
}